// Round 5
// baseline (430.372 us; speedup 1.0000x reference)
//
#include <hip/hip_runtime.h>
#include <hip/hip_bf16.h>
#include <stdint.h>

// Problem dims: B=16, C=512, H=W=32, NH=8, HC=64, HW=1024, 3C=1536
#define Bn  16
#define Cch 512
#define C3  1536
#define HWp 1024

typedef __attribute__((ext_vector_type(8))) short bf16x8;    // 8 bf16 = 4 VGPRs (MFMA A/B frag)
typedef __attribute__((ext_vector_type(4))) float f32x4;     // 16x16 MFMA C/D frag
typedef __attribute__((ext_vector_type(16))) float f32x16;   // 32x32 MFMA C/D frag

#define DEV static __device__ __forceinline__

DEV float bflo(unsigned u) { return __builtin_bit_cast(float, u << 16); }
DEV float bfhi(unsigned u) { return __builtin_bit_cast(float, u & 0xffff0000u); }
DEV unsigned short f2bf(float f) {
  __hip_bfloat16 h = __float2bfloat16(f);
  return __builtin_bit_cast(unsigned short, h);
}

// async global->LDS, 16B per lane. LDS dest must be wave-uniform base + lane*16.
DEV void async16(__hip_bfloat16* lds, const __hip_bfloat16* g) {
  __builtin_amdgcn_global_load_lds(
      (const __attribute__((address_space(1))) unsigned*)g,
      (__attribute__((address_space(3))) unsigned*)lds, 16, 0, 0);
}

// ---------------- 1. weight prep (fp32->bf16) + LayerNorm partial sums, fused ----------------
// blocks [0,8192): prep; [8192,10240): ln partial (2048 = t*1024 + b*64 + chunk)
__global__ __launch_bounds__(256) void k_prep_ln(
    const float* __restrict__ img_pw_w, const float* __restrict__ wm_pw_w,
    const float* __restrict__ proj,
    const float* __restrict__ image, const float* __restrict__ watermark,
    __hip_bfloat16* __restrict__ Wpw, __hip_bfloat16* __restrict__ projT,
    float* __restrict__ part)
{
  __shared__ float ls[4], lss[4];
  int blkid = blockIdx.x;
  if (blkid < 8192) {
    int i = blkid * 256 + threadIdx.x;
    const int NW = C3 * Cch;  // 786432
    if (i < NW)          Wpw[i] = __float2bfloat16(img_pw_w[i]);
    else if (i < 2 * NW) Wpw[i] = __float2bfloat16(wm_pw_w[i - NW]);
    else {
      int j = i - 2 * NW;                 // 0..524287
      int c = j >> 10, d = j & 1023;
      projT[(size_t)c * 1024 + d] = __float2bfloat16(proj[(size_t)d * 512 + c]);
    }
    return;
  }
  int blk = blkid - 8192;
  int chunk = blk & 63, b = (blk >> 6) & 15, t = blk >> 10;
  const float* x = (t ? watermark : image) + (size_t)b * Cch * HWp + chunk * 8192;
  const float4* xv = (const float4*)x;
  float s = 0.f, ss = 0.f;
#pragma unroll
  for (int i = 0; i < 8; i++) {
    float4 v = xv[threadIdx.x + i * 256];
    s  += v.x + v.y + v.z + v.w;
    ss += v.x * v.x + v.y * v.y + v.z * v.z + v.w * v.w;
  }
#pragma unroll
  for (int off = 32; off; off >>= 1) { s += __shfl_down(s, off); ss += __shfl_down(ss, off); }
  int wv = threadIdx.x >> 6;
  if ((threadIdx.x & 63) == 0) { ls[wv] = s; lss[wv] = ss; }
  __syncthreads();
  if (threadIdx.x == 0) {
    part[blk * 2]     = ls[0] + ls[1] + ls[2] + ls[3];
    part[blk * 2 + 1] = lss[0] + lss[1] + lss[2] + lss[3];
  }
}

// ---------------- 3. finalize mu / rstd ----------------
__global__ void k_ln_final(const float* __restrict__ part, float* __restrict__ stats)
{
  int i = threadIdx.x;
  if (i < 32) {
    float S = 0.f, SS = 0.f;
    for (int c2 = 0; c2 < 64; c2++) { S += part[(i * 64 + c2) * 2]; SS += part[(i * 64 + c2) * 2 + 1]; }
    const float inv = 1.f / (float)(Cch * HWp);
    float mu  = S * inv;
    float var = SS * inv - mu * mu;
    stats[i]      = mu;
    stats[32 + i] = rsqrtf(var + 1e-5f);
  }
}

// ---------------- 4. normalize + affine + transpose -> xnT[t][b][p][c] bf16 ----------------
__global__ __launch_bounds__(256) void k_norm_t(
    const float* __restrict__ image, const float* __restrict__ watermark,
    const float* __restrict__ img_w, const float* __restrict__ img_b,
    const float* __restrict__ wm_w,  const float* __restrict__ wm_b,
    const float* __restrict__ stats, __hip_bfloat16* __restrict__ xnT)
{
  int blk = blockIdx.x;
  int ct = blk & 15, pt = (blk >> 4) & 15, b = (blk >> 8) & 15, t = blk >> 12;
  int c0 = ct * 32, p0 = pt * 64;
  const float* x   = (t ? watermark : image) + (size_t)b * Cch * HWp;
  const float* wgt = t ? wm_w : img_w;
  const float* bia = t ? wm_b : img_b;
  float mu = stats[t * 16 + b], rstd = stats[32 + t * 16 + b];
  __shared__ float tile[32 * 66];
  int tid = threadIdx.x;
  {
    int c = tid >> 3, s = tid & 7;
    const float* xr = x   + (size_t)(c0 + c) * HWp + p0;
    const float* wr = wgt + (size_t)(c0 + c) * HWp + p0;
    const float* br = bia + (size_t)(c0 + c) * HWp + p0;
#pragma unroll
    for (int j = 0; j < 2; j++) {
      int f = s + j * 8;                 // float4 slot 0..15
      float4 xv = *(const float4*)&xr[f * 4];
      float4 wv = *(const float4*)&wr[f * 4];
      float4 bv = *(const float4*)&br[f * 4];
      float n0 = (xv.x - mu) * rstd * wv.x + bv.x;
      float n1 = (xv.y - mu) * rstd * wv.y + bv.y;
      float n2 = (xv.z - mu) * rstd * wv.z + bv.z;
      float n3 = (xv.w - mu) * rstd * wv.w + bv.w;
      *(float2*)&tile[c * 66 + f * 4]     = make_float2(n0, n1);
      *(float2*)&tile[c * 66 + f * 4 + 2] = make_float2(n2, n3);
    }
  }
  __syncthreads();
  {
    int p = tid >> 2, cq = tid & 3;      // 64 p x 4 c-groups of 8
    union { unsigned short us[8]; uint4 v4; } pk;
#pragma unroll
    for (int j = 0; j < 8; j++) pk.us[j] = f2bf(tile[(cq * 8 + j) * 66 + p]);
    __hip_bfloat16* dst = xnT + ((size_t)(t * 16 + b)) * HWp * Cch
                        + (size_t)(p0 + p) * Cch + c0 + cq * 8;
    *(uint4*)dst = pk.v4;
  }
}

// ---------------- 5. bf16 BT-GEMM core, 32x32x16 MFMA (v2) ----------------
// C[m][n] = sum_k A[m][k]*Bt[n][k]. Block tile (MT32*32) x 128, 4 waves in 2x2
// (wave = MW*32 rows x 64 cols, MW=MT32/2), BK=64, async width-16 staging.
// 32x32x16: half the MFMA instruction count of 16x16x32 at same ds_read count.
template<int MT32, int Kdim, int Ncols, bool OBF, bool HB>
DEV void gemm_core(const __hip_bfloat16* __restrict__ A,
                   const __hip_bfloat16* __restrict__ Bt,
                   const float* __restrict__ bias, void* __restrict__ Cout)
{
  constexpr int MT = MT32 * 32;
  constexpr int MW = MT32 / 2;          // 32-row m-tiles per wave
  __shared__ __hip_bfloat16 As[MT * 64];
  __shared__ __hip_bfloat16 Bs[128 * 64];
  const int tid = threadIdx.x, lane = tid & 63, wv = tid >> 6;
  const int ln = lane & 31, lh = lane >> 5;     // lane-in-32, half-select
  const int wm = (wv >> 1) * (MW * 32), wn = (wv & 1) * 64;
  const int m0 = blockIdx.y * MT, n0 = blockIdx.x * 128;
  f32x16 acc[MW][2] = {};
  const int srow = tid >> 3, sseg = (tid & 7) * 8;
  for (int k0 = 0; k0 < Kdim; k0 += 64) {
#pragma unroll
    for (int c = 0; c < MT32; c++) {
      int row = srow + c * 32;
      async16(&As[row * 64 + sseg], &A[(size_t)(m0 + row) * Kdim + k0 + sseg]);
    }
#pragma unroll
    for (int c = 0; c < 4; c++) {
      int row = srow + c * 32;
      async16(&Bs[row * 64 + sseg], &Bt[(size_t)(n0 + row) * Kdim + k0 + sseg]);
    }
    __syncthreads();   // compiler emits vmcnt(0) drain here
#pragma unroll
    for (int s = 0; s < 4; s++) {        // 4 K-steps of 16
      bf16x8 af[MW], bf2[2];
#pragma unroll
      for (int mi = 0; mi < MW; mi++)
        af[mi]  = *(const bf16x8*)&As[(wm + mi * 32 + ln) * 64 + s * 16 + lh * 8];
#pragma unroll
      for (int ni = 0; ni < 2; ni++)
        bf2[ni] = *(const bf16x8*)&Bs[(wn + ni * 32 + ln) * 64 + s * 16 + lh * 8];
#pragma unroll
      for (int mi = 0; mi < MW; mi++)
#pragma unroll
        for (int ni = 0; ni < 2; ni++)
          acc[mi][ni] = __builtin_amdgcn_mfma_f32_32x32x16_bf16(af[mi], bf2[ni], acc[mi][ni], 0, 0, 0);
    }
    __syncthreads();
  }
  // epilogue: 32x32 C/D layout: col = ln, row = (r&3) + 8*(r>>2) + 4*lh
#pragma unroll
  for (int mi = 0; mi < MW; mi++) {
#pragma unroll
    for (int ni = 0; ni < 2; ni++) {
      int ncol = n0 + wn + ni * 32 + ln;
#pragma unroll
      for (int r = 0; r < 16; r++) {
        int row = m0 + wm + mi * 32 + (r & 3) + ((r >> 2) * 8) + lh * 4;
        float y = acc[mi][ni][r];
        if (HB) y += bias[row];
        if (OBF) ((__hip_bfloat16*)Cout)[(size_t)row * Ncols + ncol] = __float2bfloat16(y);
        else     ((float*)Cout)[(size_t)row * Ncols + ncol] = y;
      }
    }
  }
}

__global__ __launch_bounds__(256) void k_pw_gemm(
    const __hip_bfloat16* __restrict__ Wpw, const __hip_bfloat16* __restrict__ xnT,
    const float* __restrict__ img_pw_b, const float* __restrict__ wm_pw_b,
    __hip_bfloat16* __restrict__ Y)
{
  int bz = blockIdx.z, t = bz >> 4;
  gemm_core<4, 512, 1024, true, true>(
      Wpw + (size_t)t * C3 * Cch,
      xnT + (size_t)bz * HWp * Cch,
      t ? wm_pw_b : img_pw_b,
      Y + (size_t)bz * C3 * HWp);
}

__global__ __launch_bounds__(256) void k_proj_gemm(
    const __hip_bfloat16* __restrict__ projT, const __hip_bfloat16* __restrict__ attnT,
    float* __restrict__ out)
{
  int b = blockIdx.z;
  gemm_core<2, 1024, 1024, false, false>(
      projT, attnT + (size_t)b * HWp * 1024, nullptr, out + (size_t)b * Cch * HWp);
}

// ---------------- 6. depthwise 3x3 grouped conv ----------------
__global__ __launch_bounds__(256) void k_dw(
    const __hip_bfloat16* __restrict__ Y,
    const float* __restrict__ img_dw_w, const float* __restrict__ img_dw_b,
    const float* __restrict__ wm_dw_w,  const float* __restrict__ wm_dw_b,
    __hip_bfloat16* __restrict__ QKV)
{
  int idx = blockIdx.x * 256 + threadIdx.x;
  int w0 = (idx & 3) * 8;
  int h  = (idx >> 2) & 31;
  int g  = __builtin_amdgcn_readfirstlane((idx >> 7) & 511);
  int tb = __builtin_amdgcn_readfirstlane(idx >> 16);
  int t  = tb >> 4;
  const float* dww = (t ? wm_dw_w : img_dw_w) + g * 81;   // 3 o x 27
  const float* dwb = (t ? wm_dw_b : img_dw_b) + g * 3;
  const __hip_bfloat16* base = Y + ((size_t)tb * C3 + g * 3) * HWp;
  float acc[3][8];
#pragma unroll
  for (int o = 0; o < 3; o++) {
    float bv = dwb[o];
#pragma unroll
    for (int w = 0; w < 8; w++) acc[o][w] = bv;
  }
  const bool mlo = (w0 == 0), mhi = (w0 == 24);
#pragma unroll
  for (int i = 0; i < 3; i++) {
#pragma unroll
    for (int kh = 0; kh < 3; kh++) {
      int hh = h + kh - 1;
      if ((unsigned)hh > 31u) continue;
      const unsigned* up = (const unsigned*)(base + i * HWp + hh * 32 + (w0 - 2));
      float v[12];
#pragma unroll
      for (int d2 = 0; d2 < 6; d2++) { unsigned u = up[d2]; v[d2*2] = bflo(u); v[d2*2+1] = bfhi(u); }
      if (mlo) { v[0] = 0.f; v[1] = 0.f; }
      if (mhi) { v[10] = 0.f; v[11] = 0.f; }
#pragma unroll
      for (int o = 0; o < 3; o++) {
        float wk0 = dww[o*27 + i*9 + kh*3 + 0];
        float wk1 = dww[o*27 + i*9 + kh*3 + 1];
        float wk2 = dww[o*27 + i*9 + kh*3 + 2];
#pragma unroll
        for (int w = 0; w < 8; w++)
          acc[o][w] += v[w + 1] * wk0 + v[w + 2] * wk1 + v[w + 3] * wk2;
      }
    }
  }
#pragma unroll
  for (int o = 0; o < 3; o++) {
    union { unsigned short us[8]; uint4 v4; } pk;
#pragma unroll
    for (int w = 0; w < 8; w++) pk.us[w] = f2bf(acc[o][w]);
    *(uint4*)(QKV + ((size_t)tb * C3 + g * 3 + o) * HWp + h * 32 + w0) = pk.v4;
  }
}

// ---------------- 7. attention scores + softmax over q ----------------
__global__ __launch_bounds__(256) void k_attn_scores(
    const __hip_bfloat16* __restrict__ QKV, __hip_bfloat16* __restrict__ ATg)
{
  int blk = blockIdx.x, kh = blk & 1, m = (blk >> 1) & 1, bn = blk >> 2;
  int b = bn >> 3, nh = bn & 7;
  int tid = threadIdx.x, lane = tid & 63, wv = tid >> 6;
  int lr = lane & 15, lq = lane >> 4;
  const __hip_bfloat16* kb =
      QKV + (((size_t)(kh * 16 + b)) * C3 + 512 + nh * 64 + (wv * 16 + lr)) * HWp + lq * 8;
  const __hip_bfloat16* qbase[4];
#pragma unroll
  for (int qt = 0; qt < 4; qt++)
    qbase[qt] = QKV + (((size_t)(m * 16 + b)) * C3 + nh * 64 + qt * 16 + lr) * HWp + lq * 8;

  f32x4 acc[4] = {};
  for (int p0 = 0; p0 < HWp; p0 += 32) {
    bf16x8 bk = *(const bf16x8*)(kb + p0);
#pragma unroll
    for (int qt = 0; qt < 4; qt++) {
      bf16x8 aq = *(const bf16x8*)(qbase[qt] + p0);
      acc[qt] = __builtin_amdgcn_mfma_f32_16x16x32_bf16(aq, bk, acc[qt], 0, 0, 0);
    }
  }
  __shared__ float S[64][65];
  __shared__ float redmax[4][64];
  __shared__ float redsum[4][64];
  __shared__ __hip_bfloat16 Ash[64][72];
#pragma unroll
  for (int qt = 0; qt < 4; qt++)
#pragma unroll
    for (int r = 0; r < 4; r++)
      S[qt * 16 + lq * 4 + r][wv * 16 + lr] = acc[qt][r];
  __syncthreads();
  int k = tid & 63, sub = tid >> 6;
  float vals[16], mx = -1e30f;
#pragma unroll
  for (int j = 0; j < 16; j++) { vals[j] = S[sub * 16 + j][k]; mx = fmaxf(mx, vals[j]); }
  redmax[sub][k] = mx;
  __syncthreads();
  float M = fmaxf(fmaxf(redmax[0][k], redmax[1][k]), fmaxf(redmax[2][k], redmax[3][k]));
  float ssum = 0.f;
#pragma unroll
  for (int j = 0; j < 16; j++) { vals[j] = __expf(vals[j] - M); ssum += vals[j]; }
  redsum[sub][k] = ssum;
  __syncthreads();
  float inv = 1.f / (redsum[0][k] + redsum[1][k] + redsum[2][k] + redsum[3][k]);
#pragma unroll
  for (int j = 0; j < 16; j++) Ash[sub * 16 + j][k] = __float2bfloat16(vals[j] * inv);
  __syncthreads();
  __hip_bfloat16* outp = ATg + ((size_t)(bn * 2 + m)) * 64 * 128 + kh * 64;
#pragma unroll
  for (int s = 0; s < 2; s++) {
    int id = tid + s * 256, row = id >> 3, seg = (id & 7) * 8;
    *(uint4*)&outp[(size_t)row * 128 + seg] = *(const uint4*)&Ash[row][seg];
  }
}

// ---------------- 8. attention output ----------------
__global__ __launch_bounds__(256) void k_attn_out(
    const __hip_bfloat16* __restrict__ QKV, const __hip_bfloat16* __restrict__ ATg,
    __hip_bfloat16* __restrict__ attnT)
{
  int blk = blockIdx.x, pc = blk & 3, bn = blk >> 2, b = bn >> 3, nh = bn & 7;
  int tid = threadIdx.x, lane = tid & 63, wv = tid >> 6;
  int lr = lane & 15, lq = lane >> 4;
  __shared__ __hip_bfloat16 ATs[2][64][136];
  __shared__ __hip_bfloat16 VTs[64][136];
#pragma unroll
  for (int m = 0; m < 2; m++) {
    const __hip_bfloat16* src = ATg + ((size_t)(bn * 2 + m)) * 64 * 128;
#pragma unroll
    for (int s = 0; s < 4; s++) {
      int id = tid + s * 256, row = id >> 4, seg = (id & 15) * 8;
      *(uint4*)&ATs[m][row][seg] = *(const uint4*)&src[row * 128 + seg];
    }
  }
  const int vk0 = (tid >> 3) * 4, vps = (tid & 7) * 8;
  for (int ps = 0; ps < 4; ps++) {
    int p0 = pc * 256 + ps * 64;
    __syncthreads();
    union { uint4 v4; unsigned short us[8]; } ld[4];
#pragma unroll
    for (int j = 0; j < 4; j++) {
      int kk = vk0 + j, tk = kk >> 6, hc = kk & 63;
      ld[j].v4 = *(const uint4*)(QKV +
          (((size_t)(tk * 16 + b)) * C3 + 1024 + nh * 64 + hc) * HWp + p0 + vps);
    }
#pragma unroll
    for (int e = 0; e < 8; e++) {
      uint2 w;
      w.x = (unsigned)ld[0].us[e] | ((unsigned)ld[1].us[e] << 16);
      w.y = (unsigned)ld[2].us[e] | ((unsigned)ld[3].us[e] << 16);
      *(uint2*)&VTs[vps + e][vk0] = w;
    }
    __syncthreads();
#pragma unroll
    for (int m = 0; m < 2; m++) {
      f32x4 oacc[4] = {};
#pragma unroll
      for (int ks = 0; ks < 4; ks++) {
        bf16x8 bv = *(const bf16x8*)&VTs[wv * 16 + lr][ks * 32 + lq * 8];
#pragma unroll
        for (int qt = 0; qt < 4; qt++) {
          bf16x8 av = *(const bf16x8*)&ATs[m][qt * 16 + lr][ks * 32 + lq * 8];
          oacc[qt] = __builtin_amdgcn_mfma_f32_16x16x32_bf16(av, bv, oacc[qt], 0, 0, 0);
        }
      }
#pragma unroll
      for (int qt = 0; qt < 4; qt++) {
        int q = qt * 16 + lq * 4;
        int d = nh * 128 + m * 64 + q;
        int p = p0 + wv * 16 + lr;
        union { unsigned short us[4]; uint2 v2; } pk;
#pragma unroll
        for (int r = 0; r < 4; r++) pk.us[r] = f2bf(oacc[qt][r]);
        *(uint2*)&attnT[((size_t)b * HWp + p) * 1024 + d] = pk.v2;
      }
    }
  }
}

extern "C" void kernel_launch(void* const* d_in, const int* in_sizes, int n_in,
                              void* d_out, int out_size, void* d_ws, size_t ws_size,
                              hipStream_t stream)
{
  (void)in_sizes; (void)n_in; (void)out_size; (void)ws_size;
  const float* image     = (const float*)d_in[0];
  const float* watermark = (const float*)d_in[1];
  const float* img_ln_w  = (const float*)d_in[2];
  const float* img_ln_b  = (const float*)d_in[3];
  const float* wm_ln_w   = (const float*)d_in[4];
  const float* wm_ln_b   = (const float*)d_in[5];
  const float* img_pw_w  = (const float*)d_in[6];
  const float* img_pw_b  = (const float*)d_in[7];
  const float* img_dw_w  = (const float*)d_in[8];
  const float* img_dw_b  = (const float*)d_in[9];
  const float* wm_pw_w   = (const float*)d_in[10];
  const float* wm_pw_b   = (const float*)d_in[11];
  const float* wm_dw_w   = (const float*)d_in[12];
  const float* wm_dw_b   = (const float*)d_in[13];
  const float* proj      = (const float*)d_in[14];

  char* ws = (char*)d_ws;
  // workspace map (high-water ~232 MiB); aliases are lifetime-disjoint:
  //   attnT aliases xnT (xnT dead after k_pw_gemm); ATg aliases Y (Y dead after k_dw)
  __hip_bfloat16* Wpw    = (__hip_bfloat16*)(ws + 0);            // 3.0 MiB
  __hip_bfloat16* projT  = (__hip_bfloat16*)(ws + 3145728);      // 1.0 MiB
  float*          lnpart = (float*)(ws + 4194304);               // 16 KiB
  float*          stats  = (float*)(ws + 4210688);               // 256 B
  __hip_bfloat16* xnT    = (__hip_bfloat16*)(ws + 5242880);      // 32 MiB
  __hip_bfloat16* attnT  = xnT;                                  // alias
  __hip_bfloat16* Y      = (__hip_bfloat16*)(ws + 41943040);     // 96 MiB
  __hip_bfloat16* ATg    = Y;                                    // alias (4 MiB)
  __hip_bfloat16* QKV    = (__hip_bfloat16*)(ws + 142606336);    // 96 MiB

  k_prep_ln<<<10240, 256, 0, stream>>>(img_pw_w, wm_pw_w, proj, image, watermark,
                                       Wpw, projT, lnpart);
  k_ln_final<<<1, 64, 0, stream>>>(lnpart, stats);
  k_norm_t<<<8192, 256, 0, stream>>>(image, watermark, img_ln_w, img_ln_b,
                                     wm_ln_w, wm_ln_b, stats, xnT);
  dim3 gpw(8, 12, 32);
  k_pw_gemm<<<gpw, 256, 0, stream>>>(Wpw, xnT, img_pw_b, wm_pw_b, Y);
  k_dw<<<8192, 256, 0, stream>>>(Y, img_dw_w, img_dw_b, wm_dw_w, wm_dw_b, QKV);
  k_attn_scores<<<512, 256, 0, stream>>>(QKV, ATg);
  k_attn_out<<<512, 256, 0, stream>>>(QKV, ATg, attnT);
  dim3 gpj(8, 8, 16);
  k_proj_gemm<<<gpj, 256, 0, stream>>>(projT, attnT, (float*)d_out);
}

// Round 6
// 364.322 us; speedup vs baseline: 1.1813x; 1.1813x over previous
//
#include <hip/hip_runtime.h>
#include <hip/hip_bf16.h>
#include <stdint.h>

// Problem dims: B=16, C=512, H=W=32, NH=8, HC=64, HW=1024, 3C=1536
#define Bn  16
#define Cch 512
#define C3  1536
#define HWp 1024

typedef __attribute__((ext_vector_type(8))) short bf16x8;    // 8 bf16 = 4 VGPRs (MFMA A/B frag)
typedef __attribute__((ext_vector_type(4))) float f32x4;     // 16x16 MFMA C/D frag

#define DEV static __device__ __forceinline__

DEV float bflo(unsigned u) { return __builtin_bit_cast(float, u << 16); }
DEV float bfhi(unsigned u) { return __builtin_bit_cast(float, u & 0xffff0000u); }
DEV unsigned short f2bf(float f) {
  __hip_bfloat16 h = __float2bfloat16(f);
  return __builtin_bit_cast(unsigned short, h);
}

// async global->LDS, 16B per lane. LDS dest must be wave-uniform base + lane*16.
DEV void async16(__hip_bfloat16* lds, const __hip_bfloat16* g) {
  __builtin_amdgcn_global_load_lds(
      (const __attribute__((address_space(1))) unsigned*)g,
      (__attribute__((address_space(3))) unsigned*)lds, 16, 0, 0);
}

// ---------------- 1. weight prep (fp32->bf16) + LayerNorm partial sums, fused ----------------
// blocks [0,8192): prep; [8192,10240): ln partial (2048 = t*1024 + b*64 + chunk)
__global__ __launch_bounds__(256) void k_prep_ln(
    const float* __restrict__ img_pw_w, const float* __restrict__ wm_pw_w,
    const float* __restrict__ proj,
    const float* __restrict__ image, const float* __restrict__ watermark,
    __hip_bfloat16* __restrict__ Wpw, __hip_bfloat16* __restrict__ projT,
    float* __restrict__ part)
{
  __shared__ float ls[4], lss[4];
  int blkid = blockIdx.x;
  if (blkid < 8192) {
    int i = blkid * 256 + threadIdx.x;
    const int NW = C3 * Cch;  // 786432
    if (i < NW)          Wpw[i] = __float2bfloat16(img_pw_w[i]);
    else if (i < 2 * NW) Wpw[i] = __float2bfloat16(wm_pw_w[i - NW]);
    else {
      int j = i - 2 * NW;                 // 0..524287
      int c = j >> 10, d = j & 1023;
      projT[(size_t)c * 1024 + d] = __float2bfloat16(proj[(size_t)d * 512 + c]);
    }
    return;
  }
  int blk = blkid - 8192;
  int chunk = blk & 63, b = (blk >> 6) & 15, t = blk >> 10;
  const float* x = (t ? watermark : image) + (size_t)b * Cch * HWp + chunk * 8192;
  const float4* xv = (const float4*)x;
  float s = 0.f, ss = 0.f;
#pragma unroll
  for (int i = 0; i < 8; i++) {
    float4 v = xv[threadIdx.x + i * 256];
    s  += v.x + v.y + v.z + v.w;
    ss += v.x * v.x + v.y * v.y + v.z * v.z + v.w * v.w;
  }
#pragma unroll
  for (int off = 32; off; off >>= 1) { s += __shfl_down(s, off); ss += __shfl_down(ss, off); }
  int wv = threadIdx.x >> 6;
  if ((threadIdx.x & 63) == 0) { ls[wv] = s; lss[wv] = ss; }
  __syncthreads();
  if (threadIdx.x == 0) {
    part[blk * 2]     = ls[0] + ls[1] + ls[2] + ls[3];
    part[blk * 2 + 1] = lss[0] + lss[1] + lss[2] + lss[3];
  }
}

// ---------------- 3. finalize mu / rstd ----------------
__global__ void k_ln_final(const float* __restrict__ part, float* __restrict__ stats)
{
  int i = threadIdx.x;
  if (i < 32) {
    float S = 0.f, SS = 0.f;
    for (int c2 = 0; c2 < 64; c2++) { S += part[(i * 64 + c2) * 2]; SS += part[(i * 64 + c2) * 2 + 1]; }
    const float inv = 1.f / (float)(Cch * HWp);
    float mu  = S * inv;
    float var = SS * inv - mu * mu;
    stats[i]      = mu;
    stats[32 + i] = rsqrtf(var + 1e-5f);
  }
}

// ---------------- 4. normalize + affine + transpose -> xnT[t][b][p][c] bf16 ----------------
__global__ __launch_bounds__(256) void k_norm_t(
    const float* __restrict__ image, const float* __restrict__ watermark,
    const float* __restrict__ img_w, const float* __restrict__ img_b,
    const float* __restrict__ wm_w,  const float* __restrict__ wm_b,
    const float* __restrict__ stats, __hip_bfloat16* __restrict__ xnT)
{
  int blk = blockIdx.x;
  int ct = blk & 15, pt = (blk >> 4) & 15, b = (blk >> 8) & 15, t = blk >> 12;
  int c0 = ct * 32, p0 = pt * 64;
  const float* x   = (t ? watermark : image) + (size_t)b * Cch * HWp;
  const float* wgt = t ? wm_w : img_w;
  const float* bia = t ? wm_b : img_b;
  float mu = stats[t * 16 + b], rstd = stats[32 + t * 16 + b];
  __shared__ float tile[32 * 66];
  int tid = threadIdx.x;
  {
    int c = tid >> 3, s = tid & 7;
    const float* xr = x   + (size_t)(c0 + c) * HWp + p0;
    const float* wr = wgt + (size_t)(c0 + c) * HWp + p0;
    const float* br = bia + (size_t)(c0 + c) * HWp + p0;
#pragma unroll
    for (int j = 0; j < 2; j++) {
      int f = s + j * 8;                 // float4 slot 0..15
      float4 xv = *(const float4*)&xr[f * 4];
      float4 wv = *(const float4*)&wr[f * 4];
      float4 bv = *(const float4*)&br[f * 4];
      float n0 = (xv.x - mu) * rstd * wv.x + bv.x;
      float n1 = (xv.y - mu) * rstd * wv.y + bv.y;
      float n2 = (xv.z - mu) * rstd * wv.z + bv.z;
      float n3 = (xv.w - mu) * rstd * wv.w + bv.w;
      *(float2*)&tile[c * 66 + f * 4]     = make_float2(n0, n1);
      *(float2*)&tile[c * 66 + f * 4 + 2] = make_float2(n2, n3);
    }
  }
  __syncthreads();
  {
    int p = tid >> 2, cq = tid & 3;      // 64 p x 4 c-groups of 8
    union { unsigned short us[8]; uint4 v4; } pk;
#pragma unroll
    for (int j = 0; j < 8; j++) pk.us[j] = f2bf(tile[(cq * 8 + j) * 66 + p]);
    __hip_bfloat16* dst = xnT + ((size_t)(t * 16 + b)) * HWp * Cch
                        + (size_t)(p0 + p) * Cch + c0 + cq * 8;
    *(uint4*)dst = pk.v4;
  }
}

// ---------------- 5. bf16 BT-GEMM core: 16x16x32 MFMA + XOR-swizzled LDS ----------------
// C[m][n] = sum_k A[m][k]*Bt[n][k]. (MI*32)x128 tile, 4 waves (MI/2*16-row x 64-col
// quadrants, 4xMI MFMA grid per wave), BK=64. async width-16 staging, UNPADDED
// [rows][64] LDS with 16B-segment XOR swizzle: LDS[row][slot] holds global segment
// (slot ^ (row&7)). Staging dest stays linear (tid*16, async constraint); readers
// use slot = seg ^ (row&7) -> all 8 segment positions covered per fragment read
// (2 lanes/bank = free) instead of 16-lanes-per-4-bank-group (the 1.9e7 conflicts).
template<int MI, int Kdim, int Ncols, bool OBF, bool HB>
DEV void gemm_core(const __hip_bfloat16* __restrict__ A,
                   const __hip_bfloat16* __restrict__ Bt,
                   const float* __restrict__ bias, void* __restrict__ Cout)
{
  constexpr int MT = MI * 32;
  __shared__ __hip_bfloat16 As[MT * 64];
  __shared__ __hip_bfloat16 Bs[128 * 64];
  const int tid = threadIdx.x, lane = tid & 63, wv = tid >> 6;
  const int lr = lane & 15, lq = lane >> 4;
  const int wm = (wv >> 1) * (MI * 16), wn = (wv & 1) * 64;
  const int m0 = blockIdx.y * MT, n0 = blockIdx.x * 128;
  f32x4 acc[MI][4] = {};
  const int srow = tid >> 3, sslot = tid & 7;
  const int sseg = (sslot ^ (srow & 7)) * 8;    // swizzled global segment (halfs)
  for (int k0 = 0; k0 < Kdim; k0 += 64) {
#pragma unroll
    for (int c = 0; c < MI; c++) {
      int row = srow + c * 32;                  // row&7 == srow&7 (c*32 mult of 8)
      async16(&As[row * 64 + sslot * 8], &A[(size_t)(m0 + row) * Kdim + k0 + sseg]);
    }
#pragma unroll
    for (int c = 0; c < 4; c++) {
      int row = srow + c * 32;
      async16(&Bs[row * 64 + sslot * 8], &Bt[(size_t)(n0 + row) * Kdim + k0 + sseg]);
    }
    __syncthreads();   // compiler emits vmcnt(0) drain here
#pragma unroll
    for (int ks = 0; ks < 2; ks++) {
      bf16x8 af[MI], bfr[4];
#pragma unroll
      for (int mi = 0; mi < MI; mi++) {
        int r = wm + mi * 16 + lr;              // r&7 == lr&7
        af[mi]  = *(const bf16x8*)&As[r * 64 + (((ks * 4 + lq) ^ (lr & 7)) * 8)];
      }
#pragma unroll
      for (int ni = 0; ni < 4; ni++) {
        int r = wn + ni * 16 + lr;
        bfr[ni] = *(const bf16x8*)&Bs[r * 64 + (((ks * 4 + lq) ^ (lr & 7)) * 8)];
      }
#pragma unroll
      for (int mi = 0; mi < MI; mi++)
#pragma unroll
        for (int ni = 0; ni < 4; ni++)
          acc[mi][ni] = __builtin_amdgcn_mfma_f32_16x16x32_bf16(af[mi], bfr[ni], acc[mi][ni], 0, 0, 0);
    }
    __syncthreads();
  }
#pragma unroll
  for (int mi = 0; mi < MI; mi++) {
    int mrow = m0 + wm + mi * 16 + lq * 4;
#pragma unroll
    for (int ni = 0; ni < 4; ni++) {
      int ncol = n0 + wn + ni * 16 + lr;
#pragma unroll
      for (int r = 0; r < 4; r++) {
        float y = acc[mi][ni][r];
        int row = mrow + r;
        if (HB) y += bias[row];
        if (OBF) ((__hip_bfloat16*)Cout)[(size_t)row * Ncols + ncol] = __float2bfloat16(y);
        else     ((float*)Cout)[(size_t)row * Ncols + ncol] = y;
      }
    }
  }
}

__global__ __launch_bounds__(256) void k_pw_gemm(
    const __hip_bfloat16* __restrict__ Wpw, const __hip_bfloat16* __restrict__ xnT,
    const float* __restrict__ img_pw_b, const float* __restrict__ wm_pw_b,
    __hip_bfloat16* __restrict__ Y)
{
  int bz = blockIdx.z, t = bz >> 4;
  gemm_core<4, 512, 1024, true, true>(
      Wpw + (size_t)t * C3 * Cch,
      xnT + (size_t)bz * HWp * Cch,
      t ? wm_pw_b : img_pw_b,
      Y + (size_t)bz * C3 * HWp);
}

__global__ __launch_bounds__(256) void k_proj_gemm(
    const __hip_bfloat16* __restrict__ projT, const __hip_bfloat16* __restrict__ attnT,
    float* __restrict__ out)
{
  int b = blockIdx.z;
  gemm_core<2, 1024, 1024, false, false>(
      projT, attnT + (size_t)b * HWp * 1024, nullptr, out + (size_t)b * Cch * HWp);
}

// ---------------- 6. depthwise 3x3 grouped conv ----------------
__global__ __launch_bounds__(256) void k_dw(
    const __hip_bfloat16* __restrict__ Y,
    const float* __restrict__ img_dw_w, const float* __restrict__ img_dw_b,
    const float* __restrict__ wm_dw_w,  const float* __restrict__ wm_dw_b,
    __hip_bfloat16* __restrict__ QKV)
{
  int idx = blockIdx.x * 256 + threadIdx.x;
  int w0 = (idx & 3) * 8;
  int h  = (idx >> 2) & 31;
  int g  = __builtin_amdgcn_readfirstlane((idx >> 7) & 511);
  int tb = __builtin_amdgcn_readfirstlane(idx >> 16);
  int t  = tb >> 4;
  const float* dww = (t ? wm_dw_w : img_dw_w) + g * 81;   // 3 o x 27
  const float* dwb = (t ? wm_dw_b : img_dw_b) + g * 3;
  const __hip_bfloat16* base = Y + ((size_t)tb * C3 + g * 3) * HWp;
  float acc[3][8];
#pragma unroll
  for (int o = 0; o < 3; o++) {
    float bv = dwb[o];
#pragma unroll
    for (int w = 0; w < 8; w++) acc[o][w] = bv;
  }
  const bool mlo = (w0 == 0), mhi = (w0 == 24);
#pragma unroll
  for (int i = 0; i < 3; i++) {
#pragma unroll
    for (int kh = 0; kh < 3; kh++) {
      int hh = h + kh - 1;
      if ((unsigned)hh > 31u) continue;
      const unsigned* up = (const unsigned*)(base + i * HWp + hh * 32 + (w0 - 2));
      float v[12];
#pragma unroll
      for (int d2 = 0; d2 < 6; d2++) { unsigned u = up[d2]; v[d2*2] = bflo(u); v[d2*2+1] = bfhi(u); }
      if (mlo) { v[0] = 0.f; v[1] = 0.f; }
      if (mhi) { v[10] = 0.f; v[11] = 0.f; }
#pragma unroll
      for (int o = 0; o < 3; o++) {
        float wk0 = dww[o*27 + i*9 + kh*3 + 0];
        float wk1 = dww[o*27 + i*9 + kh*3 + 1];
        float wk2 = dww[o*27 + i*9 + kh*3 + 2];
#pragma unroll
        for (int w = 0; w < 8; w++)
          acc[o][w] += v[w + 1] * wk0 + v[w + 2] * wk1 + v[w + 3] * wk2;
      }
    }
  }
#pragma unroll
  for (int o = 0; o < 3; o++) {
    union { unsigned short us[8]; uint4 v4; } pk;
#pragma unroll
    for (int w = 0; w < 8; w++) pk.us[w] = f2bf(acc[o][w]);
    *(uint4*)(QKV + ((size_t)tb * C3 + g * 3 + o) * HWp + h * 32 + w0) = pk.v4;
  }
}

// ---------------- 7. attention scores + softmax over q ----------------
__global__ __launch_bounds__(256) void k_attn_scores(
    const __hip_bfloat16* __restrict__ QKV, __hip_bfloat16* __restrict__ ATg)
{
  int blk = blockIdx.x, kh = blk & 1, m = (blk >> 1) & 1, bn = blk >> 2;
  int b = bn >> 3, nh = bn & 7;
  int tid = threadIdx.x, lane = tid & 63, wv = tid >> 6;
  int lr = lane & 15, lq = lane >> 4;
  const __hip_bfloat16* kb =
      QKV + (((size_t)(kh * 16 + b)) * C3 + 512 + nh * 64 + (wv * 16 + lr)) * HWp + lq * 8;
  const __hip_bfloat16* qbase[4];
#pragma unroll
  for (int qt = 0; qt < 4; qt++)
    qbase[qt] = QKV + (((size_t)(m * 16 + b)) * C3 + nh * 64 + qt * 16 + lr) * HWp + lq * 8;

  f32x4 acc[4] = {};
  for (int p0 = 0; p0 < HWp; p0 += 32) {
    bf16x8 bk = *(const bf16x8*)(kb + p0);
#pragma unroll
    for (int qt = 0; qt < 4; qt++) {
      bf16x8 aq = *(const bf16x8*)(qbase[qt] + p0);
      acc[qt] = __builtin_amdgcn_mfma_f32_16x16x32_bf16(aq, bk, acc[qt], 0, 0, 0);
    }
  }
  __shared__ float S[64][65];
  __shared__ float redmax[4][64];
  __shared__ float redsum[4][64];
  __shared__ __hip_bfloat16 Ash[64][72];
#pragma unroll
  for (int qt = 0; qt < 4; qt++)
#pragma unroll
    for (int r = 0; r < 4; r++)
      S[qt * 16 + lq * 4 + r][wv * 16 + lr] = acc[qt][r];
  __syncthreads();
  int k = tid & 63, sub = tid >> 6;
  float vals[16], mx = -1e30f;
#pragma unroll
  for (int j = 0; j < 16; j++) { vals[j] = S[sub * 16 + j][k]; mx = fmaxf(mx, vals[j]); }
  redmax[sub][k] = mx;
  __syncthreads();
  float M = fmaxf(fmaxf(redmax[0][k], redmax[1][k]), fmaxf(redmax[2][k], redmax[3][k]));
  float ssum = 0.f;
#pragma unroll
  for (int j = 0; j < 16; j++) { vals[j] = __expf(vals[j] - M); ssum += vals[j]; }
  redsum[sub][k] = ssum;
  __syncthreads();
  float inv = 1.f / (redsum[0][k] + redsum[1][k] + redsum[2][k] + redsum[3][k]);
#pragma unroll
  for (int j = 0; j < 16; j++) Ash[sub * 16 + j][k] = __float2bfloat16(vals[j] * inv);
  __syncthreads();
  __hip_bfloat16* outp = ATg + ((size_t)(bn * 2 + m)) * 64 * 128 + kh * 64;
#pragma unroll
  for (int s = 0; s < 2; s++) {
    int id = tid + s * 256, row = id >> 3, seg = (id & 7) * 8;
    *(uint4*)&outp[(size_t)row * 128 + seg] = *(const uint4*)&Ash[row][seg];
  }
}

// ---------------- 8. attention output ----------------
__global__ __launch_bounds__(256) void k_attn_out(
    const __hip_bfloat16* __restrict__ QKV, const __hip_bfloat16* __restrict__ ATg,
    __hip_bfloat16* __restrict__ attnT)
{
  int blk = blockIdx.x, pc = blk & 3, bn = blk >> 2, b = bn >> 3, nh = bn & 7;
  int tid = threadIdx.x, lane = tid & 63, wv = tid >> 6;
  int lr = lane & 15, lq = lane >> 4;
  __shared__ __hip_bfloat16 ATs[2][64][136];
  __shared__ __hip_bfloat16 VTs[64][136];
#pragma unroll
  for (int m = 0; m < 2; m++) {
    const __hip_bfloat16* src = ATg + ((size_t)(bn * 2 + m)) * 64 * 128;
#pragma unroll
    for (int s = 0; s < 4; s++) {
      int id = tid + s * 256, row = id >> 4, seg = (id & 15) * 8;
      *(uint4*)&ATs[m][row][seg] = *(const uint4*)&src[row * 128 + seg];
    }
  }
  const int vk0 = (tid >> 3) * 4, vps = (tid & 7) * 8;
  for (int ps = 0; ps < 4; ps++) {
    int p0 = pc * 256 + ps * 64;
    __syncthreads();
    union { uint4 v4; unsigned short us[8]; } ld[4];
#pragma unroll
    for (int j = 0; j < 4; j++) {
      int kk = vk0 + j, tk = kk >> 6, hc = kk & 63;
      ld[j].v4 = *(const uint4*)(QKV +
          (((size_t)(tk * 16 + b)) * C3 + 1024 + nh * 64 + hc) * HWp + p0 + vps);
    }
#pragma unroll
    for (int e = 0; e < 8; e++) {
      uint2 w;
      w.x = (unsigned)ld[0].us[e] | ((unsigned)ld[1].us[e] << 16);
      w.y = (unsigned)ld[2].us[e] | ((unsigned)ld[3].us[e] << 16);
      *(uint2*)&VTs[vps + e][vk0] = w;
    }
    __syncthreads();
#pragma unroll
    for (int m = 0; m < 2; m++) {
      f32x4 oacc[4] = {};
#pragma unroll
      for (int ks = 0; ks < 4; ks++) {
        bf16x8 bv = *(const bf16x8*)&VTs[wv * 16 + lr][ks * 32 + lq * 8];
#pragma unroll
        for (int qt = 0; qt < 4; qt++) {
          bf16x8 av = *(const bf16x8*)&ATs[m][qt * 16 + lr][ks * 32 + lq * 8];
          oacc[qt] = __builtin_amdgcn_mfma_f32_16x16x32_bf16(av, bv, oacc[qt], 0, 0, 0);
        }
      }
#pragma unroll
      for (int qt = 0; qt < 4; qt++) {
        int q = qt * 16 + lq * 4;
        int d = nh * 128 + m * 64 + q;
        int p = p0 + wv * 16 + lr;
        union { unsigned short us[4]; uint2 v2; } pk;
#pragma unroll
        for (int r = 0; r < 4; r++) pk.us[r] = f2bf(oacc[qt][r]);
        *(uint2*)&attnT[((size_t)b * HWp + p) * 1024 + d] = pk.v2;
      }
    }
  }
}

extern "C" void kernel_launch(void* const* d_in, const int* in_sizes, int n_in,
                              void* d_out, int out_size, void* d_ws, size_t ws_size,
                              hipStream_t stream)
{
  (void)in_sizes; (void)n_in; (void)out_size; (void)ws_size;
  const float* image     = (const float*)d_in[0];
  const float* watermark = (const float*)d_in[1];
  const float* img_ln_w  = (const float*)d_in[2];
  const float* img_ln_b  = (const float*)d_in[3];
  const float* wm_ln_w   = (const float*)d_in[4];
  const float* wm_ln_b   = (const float*)d_in[5];
  const float* img_pw_w  = (const float*)d_in[6];
  const float* img_pw_b  = (const float*)d_in[7];
  const float* img_dw_w  = (const float*)d_in[8];
  const float* img_dw_b  = (const float*)d_in[9];
  const float* wm_pw_w   = (const float*)d_in[10];
  const float* wm_pw_b   = (const float*)d_in[11];
  const float* wm_dw_w   = (const float*)d_in[12];
  const float* wm_dw_b   = (const float*)d_in[13];
  const float* proj      = (const float*)d_in[14];

  char* ws = (char*)d_ws;
  // workspace map (high-water ~232 MiB); aliases are lifetime-disjoint:
  //   attnT aliases xnT (xnT dead after k_pw_gemm); ATg aliases Y (Y dead after k_dw)
  __hip_bfloat16* Wpw    = (__hip_bfloat16*)(ws + 0);            // 3.0 MiB
  __hip_bfloat16* projT  = (__hip_bfloat16*)(ws + 3145728);      // 1.0 MiB
  float*          lnpart = (float*)(ws + 4194304);               // 16 KiB
  float*          stats  = (float*)(ws + 4210688);               // 256 B
  __hip_bfloat16* xnT    = (__hip_bfloat16*)(ws + 5242880);      // 32 MiB
  __hip_bfloat16* attnT  = xnT;                                  // alias
  __hip_bfloat16* Y      = (__hip_bfloat16*)(ws + 41943040);     // 96 MiB
  __hip_bfloat16* ATg    = Y;                                    // alias (4 MiB)
  __hip_bfloat16* QKV    = (__hip_bfloat16*)(ws + 142606336);    // 96 MiB

  k_prep_ln<<<10240, 256, 0, stream>>>(img_pw_w, wm_pw_w, proj, image, watermark,
                                       Wpw, projT, lnpart);
  k_ln_final<<<1, 64, 0, stream>>>(lnpart, stats);
  k_norm_t<<<8192, 256, 0, stream>>>(image, watermark, img_ln_w, img_ln_b,
                                     wm_ln_w, wm_ln_b, stats, xnT);
  dim3 gpw(8, 12, 32);
  k_pw_gemm<<<gpw, 256, 0, stream>>>(Wpw, xnT, img_pw_b, wm_pw_b, Y);
  k_dw<<<8192, 256, 0, stream>>>(Y, img_dw_w, img_dw_b, wm_dw_w, wm_dw_b, QKV);
  k_attn_scores<<<512, 256, 0, stream>>>(QKV, ATg);
  k_attn_out<<<512, 256, 0, stream>>>(QKV, ATg, attnT);
  dim3 gpj(8, 8, 16);
  k_proj_gemm<<<gpj, 256, 0, stream>>>(projT, attnT, (float*)d_out);
}